// Round 7
// baseline (233.945 us; speedup 1.0000x reference)
//
#include <hip/hip_runtime.h>

// out[b,i,j,d] = sum_{k<c} A[b,i,k,d] * B[b,k,j,d]   for i,j < c, else 0
// A: (256,64,64,32) f32, strides: b:131072, i:2048, k:32, d:1
// B: (256,64,64,32) f32, strides: b:131072, k:2048, j:32, d:1
//
// v7: 2-phase double-buffered LDS pipeline (T3-lite + T14 reg-staged split).
//  - block = (b, 8-row i-chunk), 512 thr, grid order ic*256+b (XCD locality)
//  - per k-tile (KT=4): stage B-tile 32KB + A-tile 4KB into LDS via wide
//    float4 global loads issued BEFORE the compute phase, ds_write AFTER the
//    barrier -> HBM latency hides under compute; inner loop is pure LDS.
//  - compute thread = (d4, j): B read = contiguous 1KB/wave ds_read_b128
//    (conflict-free), A read = 8-way broadcast (conflict-free).
// Rationale: v1-v6 all latency-bound (VALUBusy<=16%, HBM<=33%): k-loop was
// issue-scalar-loads -> vmcnt(0) -> FMA, ~500cyc/wave/k. LDS inner loop
// breaks the dependence on global latency.

#define BATCH 256
#define NN 64
#define ND 32
#define BSTRIDE (NN * NN * ND)   // 131072
#define RSTRIDE (NN * ND)        // 2048
#define ICHUNK 8
#define KT 4
#define BT_F (KT * NN * ND)      // 8192 floats = 32 KB
#define AT_F (ICHUNK * KT * ND)  // 1024 floats = 4 KB

#define COMPUTE_KK(kk)                                                          \
    {                                                                           \
        float4 bb = *reinterpret_cast<const float4*>(                           \
            bt + (kk) * (NN * ND) + j * ND + d4 * 4);                           \
        _Pragma("unroll")                                                       \
        for (int u = 0; u < ICHUNK; ++u) {                                      \
            float4 a = *reinterpret_cast<const float4*>(                        \
                at + u * (KT * ND) + (kk) * ND + d4 * 4);                       \
            acc[u][0] = fmaf(a.x, bb.x, acc[u][0]);                             \
            acc[u][1] = fmaf(a.y, bb.y, acc[u][1]);                             \
            acc[u][2] = fmaf(a.z, bb.z, acc[u][2]);                             \
            acc[u][3] = fmaf(a.w, bb.w, acc[u][3]);                             \
        }                                                                       \
    }

__global__ __launch_bounds__(512, 2) void mp_kernel(
    const float* __restrict__ A, const float* __restrict__ B,
    const int* __restrict__ counts, float* __restrict__ out)
{
    __shared__ float Bt[2][BT_F];
    __shared__ float At[2][AT_F];

    const int b   = blockIdx.x & (BATCH - 1);
    const int ic  = blockIdx.x >> 8;         // 0..7
    const int i0  = ic * ICHUNK;
    const int c   = counts[b];
    const int tid = (int)threadIdx.x;

    const int d4 = tid & 7;                  // d float4-index: d = 4*d4..4*d4+3
    const int j  = tid >> 3;                 // 0..63

    const size_t base = (size_t)b * BSTRIDE;
    float* __restrict__ Ob = out + base + (size_t)i0 * RSTRIDE + (size_t)j * ND + d4 * 4;

    // fast path: whole i-chunk invalid -> zero-fill and retire (block-uniform)
    if (i0 >= c) {
        const float4 z = make_float4(0.f, 0.f, 0.f, 0.f);
        #pragma unroll
        for (int u = 0; u < ICHUNK; ++u)
            *reinterpret_cast<float4*>(Ob + (size_t)u * RSTRIDE) = z;
        return;
    }

    const int nt = (c + KT - 1) / KT;        // k-tiles, uniform per block

    // staging sources (flat float4 indices)
    // B-tile t is a contiguous 32KB block: B + base + t*KT*RSTRIDE
    const float4* __restrict__ Bg = reinterpret_cast<const float4*>(B + base);
    // A staging: thread tid<256 loads row i0+(tid>>5), 16B chunk (tid&31)
    const float* __restrict__ Agrow =
        A + base + (size_t)(i0 + ((tid & 255) >> 5)) * RSTRIDE;

    float4 rB[4];
    float4 rA = make_float4(0.f, 0.f, 0.f, 0.f);

    // ---- prologue: stage tile 0 (load + write + barrier)
    #pragma unroll
    for (int s = 0; s < 4; ++s) rB[s] = Bg[tid + s * 512];
    if (tid < 256) rA = *(reinterpret_cast<const float4*>(Agrow) + (tid & 31));
    #pragma unroll
    for (int s = 0; s < 4; ++s)
        reinterpret_cast<float4*>(Bt[0])[tid + s * 512] = rB[s];
    if (tid < 256) reinterpret_cast<float4*>(At[0])[tid] = rA;
    __syncthreads();

    float acc[ICHUNK][4];
    #pragma unroll
    for (int u = 0; u < ICHUNK; ++u)
        #pragma unroll
        for (int dd = 0; dd < 4; ++dd) acc[u][dd] = 0.f;

    const bool act = (j < c);                // this thread's column valid

    for (int t = 0; t < nt; ++t) {
        const int cur = t & 1;
        const bool pf = (t + 1 < nt);

        // issue next tile's global loads EARLY (latency hides under compute)
        if (pf) {
            #pragma unroll
            for (int s = 0; s < 4; ++s)
                rB[s] = Bg[(t + 1) * (BT_F / 4) + tid + s * 512];
            if (tid < 256)
                rA = *(reinterpret_cast<const float4*>(Agrow + (t + 1) * (KT * ND)) + (tid & 31));
        }

        // compute on current tile from LDS
        const int rem  = c - t * KT;
        const int kmax = (rem >= KT) ? KT : rem;
        if (act) {
            const float* __restrict__ bt = Bt[cur];
            const float* __restrict__ at = At[cur];
            if (kmax == KT) {
                #pragma unroll
                for (int kk = 0; kk < KT; ++kk) COMPUTE_KK(kk);
            } else {
                for (int kk = 0; kk < kmax; ++kk) COMPUTE_KK(kk);
            }
        }

        __syncthreads();   // everyone done reading buf[cur^1]'s previous use

        // land the staged data (vmcnt waits resolve here, after compute)
        if (pf) {
            #pragma unroll
            for (int s = 0; s < 4; ++s)
                reinterpret_cast<float4*>(Bt[cur ^ 1])[tid + s * 512] = rB[s];
            if (tid < 256) reinterpret_cast<float4*>(At[cur ^ 1])[tid] = rA;
        }

        __syncthreads();   // next tile's LDS visible to all
    }

    // masked store (output poisoned before timing -> write everything)
    #pragma unroll
    for (int u = 0; u < ICHUNK; ++u) {
        const bool v = act && ((i0 + u) < c);
        const float4 o = v ? make_float4(acc[u][0], acc[u][1], acc[u][2], acc[u][3])
                           : make_float4(0.f, 0.f, 0.f, 0.f);
        *reinterpret_cast<float4*>(Ob + (size_t)u * RSTRIDE) = o;
    }
}

extern "C" void kernel_launch(void* const* d_in, const int* in_sizes, int n_in,
                              void* d_out, int out_size, void* d_ws, size_t ws_size,
                              hipStream_t stream)
{
    const float* A      = (const float*)d_in[0];
    const float* B      = (const float*)d_in[1];
    const int*   counts = (const int*)d_in[2];
    float* out = (float*)d_out;

    mp_kernel<<<dim3(BATCH * (NN / ICHUNK)), dim3(512), 0, stream>>>(A, B, counts, out);
}

// Round 8
// 104.540 us; speedup vs baseline: 2.2378x; 2.2378x over previous
//
#include <hip/hip_runtime.h>

// out[b,i,j,d] = sum_{k<c} A[b,i,k,d] * B[b,k,j,d]   for i,j < c, else 0
// A: (256,64,64,32) f32, strides: b:131072, i:2048, k:32, d:1
// B: (256,64,64,32) f32, strides: b:131072, k:2048, j:32, d:1
//
// v8: compose the two proven wins, drop the losers.
//  - v2's body (best inner loop: 98us) unchanged.
//  - v5's longest-first schedule (sorting whales first helped) BUT
//    bucketed per-XCD: bucket = b&7, slot s -> bucket[s&7][s>>3], so
//    blockIdx%8 (the XCD round-robin) stays == b%8 -> same-batch blocks
//    share an XCD's L2 (v2's FETCH=105MB vs v5's 190MB).
//  - zero-fill items scheduled last (flood the drain phase).
// v7 lesson (LDS staging): 234us, FETCH 2.3x -- staging kills the implicit
// L2 reuse and the compute phase is too short to hide staged-load latency.

#define BATCH 256
#define NN 64
#define ND 32
#define BSTRIDE (NN * NN * ND)   // 131072
#define RSTRIDE (NN * ND)        // 2048
#define ICHUNK 8
#define NITEMS (BATCH * (NN / ICHUNK))  // 2048, item w = b*8 + ic

// ---------------- prologue: per-XCD-bucket counting sort --------------------
__global__ __launch_bounds__(512) void mp_prologue(
    const int* __restrict__ counts, int* __restrict__ items)
{
    __shared__ int cLds[BATCH];
    __shared__ int hist[8][NN + 1];  // key 0..63 = valid (64-c): whales first; 64 = zero-fill
    __shared__ int offs[8][NN + 1];
    const int tid = (int)threadIdx.x;

    for (int x = tid; x < 8 * (NN + 1); x += 512)
        (&hist[0][0])[x] = 0;
    for (int b = tid; b < BATCH; b += 512) cLds[b] = counts[b];
    __syncthreads();

    for (int w = tid; w < NITEMS; w += 512) {
        const int b = w >> 3, ic = w & 7;
        const int c = cLds[b];
        const int key = (ic * ICHUNK < c) ? (NN - c) : NN;
        atomicAdd(&hist[b & 7][key], 1);
    }
    __syncthreads();

    if (tid < 8) {  // serial 65-entry exclusive scan per bucket
        int acc = 0;
        for (int k = 0; k <= NN; ++k) { offs[tid][k] = acc; acc += hist[tid][k]; }
    }
    __syncthreads();

    for (int w = tid; w < NITEMS; w += 512) {
        const int b = w >> 3, ic = w & 7;
        const int c = cLds[b];
        const int key = (ic * ICHUNK < c) ? (NN - c) : NN;
        const int pos = atomicAdd(&offs[b & 7][key], 1);  // rank within bucket
        items[pos * 8 + (b & 7)] = w;                     // slot%8 == b%8
    }
}

// ---------------- main body (v2's proven inner loop, unchanged) -------------
__device__ __forceinline__ void mp_body(
    int b, int ic,
    const float* __restrict__ A, const float* __restrict__ B,
    const int* __restrict__ counts, float* __restrict__ out)
{
    const int i0 = ic << 3;
    const int c  = counts[b];
    const int tid = (int)threadIdx.x;
    const int d  = tid & 31;             // channel
    const int jg = tid >> 5;             // 0..15, group of 4 j's
    const int jb = jg << 2;              // j base

    const size_t base = (size_t)b * BSTRIDE;
    float* __restrict__ Ob = out + base + (size_t)i0 * RSTRIDE + (size_t)jb * ND + d;

    if (i0 >= c) {
        #pragma unroll
        for (int ii = 0; ii < ICHUNK; ++ii)
            #pragma unroll
            for (int jj = 0; jj < 4; ++jj)
                Ob[(size_t)ii * RSTRIDE + jj * ND] = 0.0f;
        return;
    }

    const float* __restrict__ Ai = A + base + (size_t)i0 * RSTRIDE + d;
    const float* __restrict__ Bb = B + base + (size_t)jb * ND + d;

    float acc[ICHUNK][4];
    #pragma unroll
    for (int ii = 0; ii < ICHUNK; ++ii)
        #pragma unroll
        for (int jj = 0; jj < 4; ++jj)
            acc[ii][jj] = 0.0f;

    const bool waveActive = (((tid >> 6) << 3) < c);

    if (waveActive) {
        #pragma unroll 2
        for (int k = 0; k < c; ++k) {
            float av[ICHUNK];
            #pragma unroll
            for (int ii = 0; ii < ICHUNK; ++ii)
                av[ii] = Ai[(size_t)ii * RSTRIDE + k * ND];
            float bv[4];
            #pragma unroll
            for (int jj = 0; jj < 4; ++jj)
                bv[jj] = Bb[(size_t)k * RSTRIDE + jj * ND];
            #pragma unroll
            for (int ii = 0; ii < ICHUNK; ++ii)
                #pragma unroll
                for (int jj = 0; jj < 4; ++jj)
                    acc[ii][jj] = fmaf(av[ii], bv[jj], acc[ii][jj]);
        }
    }

    #pragma unroll
    for (int ii = 0; ii < ICHUNK; ++ii) {
        const bool iv = (i0 + ii) < c;
        #pragma unroll
        for (int jj = 0; jj < 4; ++jj) {
            const bool v = iv && ((jb + jj) < c);
            Ob[(size_t)ii * RSTRIDE + jj * ND] = v ? acc[ii][jj] : 0.0f;
        }
    }
}

__global__ __launch_bounds__(512, 2) void mp_kernel_sorted(
    const float* __restrict__ A, const float* __restrict__ B,
    const int* __restrict__ counts, float* __restrict__ out,
    const int* __restrict__ items)
{
    const int w = items[blockIdx.x];
    mp_body(w >> 3, w & 7, A, B, counts, out);
}

__global__ __launch_bounds__(512, 2) void mp_kernel_direct(
    const float* __restrict__ A, const float* __restrict__ B,
    const int* __restrict__ counts, float* __restrict__ out)
{
    mp_body(blockIdx.x & (BATCH - 1), blockIdx.x >> 8, A, B, counts, out);
}

extern "C" void kernel_launch(void* const* d_in, const int* in_sizes, int n_in,
                              void* d_out, int out_size, void* d_ws, size_t ws_size,
                              hipStream_t stream)
{
    const float* A      = (const float*)d_in[0];
    const float* B      = (const float*)d_in[1];
    const int*   counts = (const int*)d_in[2];
    float* out = (float*)d_out;

    if (ws_size >= NITEMS * sizeof(int)) {
        int* items = (int*)d_ws;
        mp_prologue<<<dim3(1), dim3(512), 0, stream>>>(counts, items);
        mp_kernel_sorted<<<dim3(NITEMS), dim3(512), 0, stream>>>(A, B, counts, out, items);
    } else {
        mp_kernel_direct<<<dim3(NITEMS), dim3(512), 0, stream>>>(A, B, counts, out);
    }
}